// Round 12
// baseline (149.223 us; speedup 1.0000x reference)
//
#include <hip/hip_runtime.h>

#define DIM 1024
#define NHEADS 16
#define HDIM 64
#define BATCH 2
#define SEQ 2048
#define MTOT (BATCH*SEQ)
// 1/sqrt(64) * log2(e), folded into Q so softmax uses exp2
#define QSCALE 0.18033688011112042f
#define XN ((size_t)MTOT*DIM)
#define WN ((size_t)DIM*DIM)

typedef __attribute__((ext_vector_type(8))) short short8;
typedef __attribute__((ext_vector_type(4))) float f32x4;
typedef __attribute__((ext_vector_type(16))) float f32x16;
typedef __attribute__((ext_vector_type(2))) int int2v;

static __device__ __forceinline__ unsigned short bf16rne(float f) {
    unsigned u = __builtin_bit_cast(unsigned, f);
    return (unsigned short)((u + 0x7fffu + ((u >> 16) & 1u)) >> 16);
}
static __device__ __forceinline__ float bf2f(unsigned short u) {
    return __builtin_bit_cast(float, (unsigned)u << 16);
}

// async global->LDS, 16B per lane; LDS dest must be wave-uniform (HW adds lane*16).
static __device__ __forceinline__ void gld16(const void* g, void* l) {
    __builtin_amdgcn_global_load_lds((const __attribute__((address_space(1))) void*)g,
                                     (__attribute__((address_space(3))) void*)l, 16, 0, 0);
}

static __device__ __forceinline__ f32x16 mfma32(short8 a, short8 b, f32x16 c) {
    return __builtin_amdgcn_mfma_f32_32x32x16_bf16(a, b, c, 0, 0, 0);
}

// ---------------- fused f32 -> bf16 convert of x + 4 weights ----------------
__global__ __launch_bounds__(256)
void prep(const float* __restrict__ x, const float* __restrict__ wq, const float* __restrict__ wk,
          const float* __restrict__ wv, const float* __restrict__ wo, unsigned short* __restrict__ dst)
{
    const size_t i = ((size_t)blockIdx.x*256 + threadIdx.x)*8;
    const float* s; size_t o;
    if (i < XN)           { s = x;  o = i; }
    else if (i < XN+WN)   { s = wq; o = i - XN; }
    else if (i < XN+2*WN) { s = wk; o = i - XN - WN; }
    else if (i < XN+3*WN) { s = wv; o = i - XN - 2*WN; }
    else                  { s = wo; o = i - XN - 3*WN; }
    float4 a = *(const float4*)(s + o);
    float4 b = *(const float4*)(s + o + 4);
    uint4 w;
    w.x = (unsigned)bf16rne(a.x) | ((unsigned)bf16rne(a.y) << 16);
    w.y = (unsigned)bf16rne(a.z) | ((unsigned)bf16rne(a.w) << 16);
    w.z = (unsigned)bf16rne(b.x) | ((unsigned)bf16rne(b.y) << 16);
    w.w = (unsigned)bf16rne(b.z) | ((unsigned)bf16rne(b.w) << 16);
    *(uint4*)&dst[i] = w;
}

// ---------------- fused QKV bf16 GEMM, counted-vmcnt pipeline, 3 blocks/CU ----------------
__global__ __launch_bounds__(256)
void gemm_qkv(const unsigned short* __restrict__ A,
              const unsigned short* __restrict__ W0, const unsigned short* __restrict__ W1,
              const unsigned short* __restrict__ W2,
              const float* __restrict__ b0, const float* __restrict__ b1, const float* __restrict__ b2,
              unsigned short* __restrict__ o0, unsigned short* __restrict__ o1, unsigned short* __restrict__ o2)
{
    __shared__ __align__(16) unsigned short As[3][4096];
    __shared__ __align__(16) unsigned short Bs[3][4096];
    const int t = threadIdx.x, wid = t >> 6, lane = t & 63;
    const int lr = lane & 15, lg = lane >> 4;
    const int bid = blockIdx.y * 24 + blockIdx.x;
    const int swz = (bid & 7) * 96 + (bid >> 3);
    const int sx = swz % 24, sy = swz / 24;
    const int widx = sx >> 3;
    const int n0 = (sx & 7) << 7;
    const int m0 = sy << 7;
    const unsigned short* W = widx == 0 ? W0 : (widx == 1 ? W1 : W2);
    const float* bias        = widx == 0 ? b0 : (widx == 1 ? b1 : b2);
    const float scale        = widx == 0 ? QSCALE : 1.0f;
    unsigned short* out      = widx == 0 ? o0 : (widx == 1 ? o1 : o2);

    const int wm = wid >> 1, wn = wid & 1;
    const int f0 = 2*wid, f1 = f0 + 1;
    const unsigned short* Ag0 = A + (size_t)(m0 + f0*16 + lr)*DIM + lg*8;
    const unsigned short* Ag1 = A + (size_t)(m0 + f1*16 + lr)*DIM + lg*8;
    const unsigned short* Bg0 = W + (size_t)(n0 + f0*16 + lr)*DIM + lg*8;
    const unsigned short* Bg1 = W + (size_t)(n0 + f1*16 + lr)*DIM + lg*8;

    auto stage = [&](int tt, int slot) {
        const int ko = tt * 32;
        gld16(Ag0 + ko, &As[slot][f0*512]); gld16(Ag1 + ko, &As[slot][f1*512]);
        gld16(Bg0 + ko, &Bs[slot][f0*512]); gld16(Bg1 + ko, &Bs[slot][f1*512]);
    };

    f32x4 acc[4][4] = {};
    stage(0, 0); stage(1, 1);
    int c0 = 0, c1 = 1, c2 = 2;

    for (int it = 0; it < DIM/32; ++it) {
        if (it < DIM/32 - 2) { asm volatile("s_waitcnt vmcnt(4)" ::: "memory"); }
        else                 { asm volatile("s_waitcnt vmcnt(0)" ::: "memory"); }
        __builtin_amdgcn_s_barrier();
        short8 af[4], bf[4];
        #pragma unroll
        for (int i = 0; i < 4; ++i) af[i] = *(const short8*)&As[c0][(wm*4+i)*512 + lane*8];
        #pragma unroll
        for (int i = 0; i < 4; ++i) bf[i] = *(const short8*)&Bs[c0][(wn*4+i)*512 + lane*8];
        if (it + 2 < DIM/32) stage(it + 2, c2);
        __builtin_amdgcn_s_setprio(1);
        #pragma unroll
        for (int mb = 0; mb < 4; ++mb)
            #pragma unroll
            for (int nb = 0; nb < 4; ++nb)
                acc[mb][nb] = __builtin_amdgcn_mfma_f32_16x16x32_bf16(af[mb], bf[nb], acc[mb][nb], 0, 0, 0);
        __builtin_amdgcn_s_setprio(0);
        const int tmp = c0; c0 = c1; c1 = c2; c2 = tmp;
    }

    #pragma unroll
    for (int nb = 0; nb < 4; ++nb) {
        const int col = n0 + wn*64 + nb*16 + lr;
        const float bv = bias[col];
        #pragma unroll
        for (int mb = 0; mb < 4; ++mb) {
            #pragma unroll
            for (int j = 0; j < 4; ++j) {
                const int row = m0 + wm*64 + mb*16 + lg*4 + j;
                out[(size_t)row*DIM + col] = bf16rne((acc[mb][nb][j] + bv) * scale);
            }
        }
    }
}

// ---------------- O-projection GEMM: 64x128 tile, counted-vmcnt, f32 out ----------------
__global__ __launch_bounds__(256)
void gemm_o(const unsigned short* __restrict__ A, const unsigned short* __restrict__ W,
            const float* __restrict__ bias, float* __restrict__ fo)
{
    __shared__ __align__(16) unsigned short As[3][2048];
    __shared__ __align__(16) unsigned short Bs[3][4096];
    const int t = threadIdx.x, wid = t >> 6, lane = t & 63;
    const int lr = lane & 15, lg = lane >> 4;
    const int bid = blockIdx.y * 8 + blockIdx.x;
    const int swz = (bid & 7) * 64 + (bid >> 3);
    const int n0 = (swz & 7) << 7;
    const int m0 = (swz >> 3) << 6;
    const int wm = wid >> 1, wn = wid & 1;

    const int fa = wid;
    const int g0 = 2*wid, g1 = g0 + 1;
    const unsigned short* Ag  = A + (size_t)(m0 + fa*16 + lr)*DIM + lg*8;
    const unsigned short* Bg0 = W + (size_t)(n0 + g0*16 + lr)*DIM + lg*8;
    const unsigned short* Bg1 = W + (size_t)(n0 + g1*16 + lr)*DIM + lg*8;

    auto stage = [&](int tt, int slot) {
        const int ko = tt * 32;
        gld16(Ag + ko, &As[slot][fa*512]);
        gld16(Bg0 + ko, &Bs[slot][g0*512]); gld16(Bg1 + ko, &Bs[slot][g1*512]);
    };

    f32x4 acc[2][4] = {};
    stage(0, 0); stage(1, 1);
    int c0 = 0, c1 = 1, c2 = 2;

    for (int it = 0; it < DIM/32; ++it) {
        if (it < DIM/32 - 2) { asm volatile("s_waitcnt vmcnt(3)" ::: "memory"); }
        else                 { asm volatile("s_waitcnt vmcnt(0)" ::: "memory"); }
        __builtin_amdgcn_s_barrier();
        short8 af[2], bf[4];
        #pragma unroll
        for (int i = 0; i < 2; ++i) af[i] = *(const short8*)&As[c0][(wm*2+i)*512 + lane*8];
        #pragma unroll
        for (int i = 0; i < 4; ++i) bf[i] = *(const short8*)&Bs[c0][(wn*4+i)*512 + lane*8];
        if (it + 2 < DIM/32) stage(it + 2, c2);
        __builtin_amdgcn_s_setprio(1);
        #pragma unroll
        for (int mb = 0; mb < 2; ++mb)
            #pragma unroll
            for (int nb = 0; nb < 4; ++nb)
                acc[mb][nb] = __builtin_amdgcn_mfma_f32_16x16x32_bf16(af[mb], bf[nb], acc[mb][nb], 0, 0, 0);
        __builtin_amdgcn_s_setprio(0);
        const int tmp = c0; c0 = c1; c1 = c2; c2 = tmp;
    }

    #pragma unroll
    for (int nb = 0; nb < 4; ++nb) {
        const int col = n0 + wn*64 + nb*16 + lr;
        const float bv = bias[col];
        #pragma unroll
        for (int mb = 0; mb < 2; ++mb) {
            #pragma unroll
            for (int j = 0; j < 4; ++j) {
                const int row = m0 + wm*32 + mb*16 + lg*4 + j;
                fo[(size_t)row*DIM + col] = acc[mb][nb][j] + bv;
            }
        }
    }
}

// ---------------- K/V pack: row-major -> attention-fragment-linear ----------------
__global__ __launch_bounds__(256)
void pack_kv(const unsigned short* __restrict__ Kg, const unsigned short* __restrict__ V,
             unsigned short* __restrict__ Kp, unsigned short* __restrict__ Vp)
{
    __shared__ unsigned short tile[64][66];
    const int t  = threadIdx.x;
    const int st = blockIdx.x;
    const int bh = blockIdx.y;
    const int isV = blockIdx.z;
    const int b = bh >> 4, h = bh & 15;
    const unsigned short* src = isV ? V : Kg;
    unsigned short* dstb = (isV ? Vp : Kp) + ((size_t)bh*32 + st)*4096;
    const int sr = t >> 3;
    const int dc = (t & 7) * 8;

    #pragma unroll
    for (int r = 0; r < 2; ++r) {
        const int s = r*32 + sr;
        short8 v = *(const short8*)(src + (size_t)(b*SEQ + st*64 + s)*DIM + h*HDIM + dc);
        #pragma unroll
        for (int e = 0; e < 8; ++e) tile[s][dc + e] = (unsigned short)v[e];
    }
    __syncthreads();
    #pragma unroll
    for (int r = 0; r < 2; ++r) {
        const int idx = t + r*256;
        const int fr = idx >> 6, ln = idx & 63;
        short8 ov;
        if (isV) {
            const int s0 = (fr & 3)*16 + (ln >> 5)*8;
            const int d  = (fr >> 2)*32 + (ln & 31);
            #pragma unroll
            for (int e = 0; e < 8; ++e) ov[e] = (short)tile[s0 + e][d];
        } else {
            const int key = (fr >> 2)*32 + (ln & 31);
            const int d0  = (fr & 3)*16 + (ln >> 5)*8;
            #pragma unroll
            for (int e = 0; e < 8; ++e) ov[e] = (short)tile[key][d0 + e];
        }
        *(short8*)(dstb + fr*512 + ln*8) = ov;
    }
}

// ---------------- split-K MFMA flash attention ----------------
// grid (16 qt, 32 bh, 2 kz) = 1024 blocks, 4 waves each -> 16 waves/CU (2x TLP).
// Each block: 128 q-rows x 1024 keys (16 tiles of 64). 2-slot LDS ring (32KB ->
// 4 blocks/CU). Writes UNNORMALIZED ctx partials (bf16) + lsum partials (f32);
// combine kernel does (c0+c1)/(l0+l1).
struct PA { short8 p[4]; };

static __device__ __forceinline__ PA softmax_pack(const f32x16& s0, const f32x16& s1, float& lsum) {
    float rsum = 0.f;
    unsigned pw0[4][2], pw1[4][2];
    #pragma unroll
    for (int r1 = 0; r1 < 4; ++r1)
        #pragma unroll
        for (int tt = 0; tt < 2; ++tt) {
            float pa_ = __builtin_amdgcn_exp2f(s0[4*r1+2*tt]);
            float pb_ = __builtin_amdgcn_exp2f(s0[4*r1+2*tt+1]);
            float pc_ = __builtin_amdgcn_exp2f(s1[4*r1+2*tt]);
            float pd_ = __builtin_amdgcn_exp2f(s1[4*r1+2*tt+1]);
            rsum += (pa_ + pb_) + (pc_ + pd_);
            asm("v_cvt_pk_bf16_f32 %0, %1, %2" : "=v"(pw0[r1][tt]) : "v"(pa_), "v"(pb_));
            asm("v_cvt_pk_bf16_f32 %0, %1, %2" : "=v"(pw1[r1][tt]) : "v"(pc_), "v"(pd_));
        }
    rsum += __shfl_xor(rsum, 32);
    lsum += rsum;
    PA r;
    #pragma unroll
    for (int ss = 0; ss < 4; ++ss) {
        union { short8 s8; unsigned u[4]; } pu;
        #pragma unroll
        for (int tt = 0; tt < 2; ++tt) {
            const unsigned a = (ss >> 1) ? pw1[2*(ss&1)][tt]   : pw0[2*(ss&1)][tt];
            const unsigned b = (ss >> 1) ? pw1[2*(ss&1)+1][tt] : pw0[2*(ss&1)+1][tt];
            int2v sw = __builtin_amdgcn_permlane32_swap((int)a, (int)b, false, false);
            pu.u[tt]     = (unsigned)sw[0];
            pu.u[2 + tt] = (unsigned)sw[1];
        }
        r.p[ss] = pu.s8;
    }
    return r;
}

__global__ __launch_bounds__(256)
void attn_ks(const unsigned short* __restrict__ Q, const unsigned short* __restrict__ Kp,
             const unsigned short* __restrict__ Vp,
             unsigned short* __restrict__ Pc, float* __restrict__ Pl)
{
    __shared__ __align__(16) unsigned short Ks[2][4096];
    __shared__ __align__(16) unsigned short Vs[2][4096];
    const int t = threadIdx.x, wid = t >> 6, lane = t & 63;
    const int l31 = lane & 31, h = lane >> 5;
    const int bid = blockIdx.y * 16 + blockIdx.x;
    const int swz = (bid & 7) * 64 + (bid >> 3);
    const int qt = swz & 15, bh = swz >> 4;
    const int kz = blockIdx.z;
    const int b = bh >> 4, hh = bh & 15;
    const unsigned short* Qb = Q + (size_t)b*SEQ*DIM + (size_t)hh*HDIM;
    const int q0 = qt*128 + wid*32;

    short8 qf[4];   // Q as B-operand: lane holds Q[q0+l31][ds*16 + h*8 + e]
    #pragma unroll
    for (int ds = 0; ds < 4; ++ds)
        qf[ds] = *(const short8*)&Qb[(size_t)(q0 + l31)*DIM + ds*16 + h*8];

    const int f0 = 2*wid, f1 = f0 + 1;
    const size_t kvbase = (size_t)(bh*32 + kz*16)*4096;
    const unsigned short* Kg0 = Kp + kvbase + f0*512 + lane*8;
    const unsigned short* Kg1 = Kg0 + 512;
    const unsigned short* Vg0 = Vp + kvbase + f0*512 + lane*8;
    const unsigned short* Vg1 = Vg0 + 512;

    auto stage = [&](int tn) {   // tn < 16
        const size_t ko = (size_t)tn * 4096;
        const int sl = tn & 1;
        gld16(Kg0 + ko, &Ks[sl][f0*512]); gld16(Kg1 + ko, &Ks[sl][f1*512]);
        gld16(Vg0 + ko, &Vs[sl][f0*512]); gld16(Vg1 + ko, &Vs[sl][f1*512]);
    };

    f32x16 ctx0 = {}, ctx1 = {};
    float lsum = 0.0f;

    stage(0);

    for (int tn = 0; tn < 16; ++tn) {
        const int sl = tn & 1;
        // stage(tn) landed (drain); with 16 waves/CU other blocks hide the stall
        asm volatile("s_waitcnt vmcnt(0)" ::: "memory");
        __builtin_amdgcn_s_barrier();   // slot (tn+1)&1 reads (tile tn-1) done block-wide
        if (tn + 1 < 16) stage(tn + 1);

        // S^T = K Q^T
        f32x16 s0 = {}, s1 = {};
        __builtin_amdgcn_s_setprio(1);
        #pragma unroll
        for (int ds = 0; ds < 4; ++ds) {
            short8 kf0 = *(const short8*)&Ks[sl][ds*512 + lane*8];
            short8 kf1 = *(const short8*)&Ks[sl][(4+ds)*512 + lane*8];
            s0 = mfma32(kf0, qf[ds], s0);
            s1 = mfma32(kf1, qf[ds], s1);
        }
        __builtin_amdgcn_s_setprio(0);

        PA pa = softmax_pack(s0, s1, lsum);

        // O += P @ V
        __builtin_amdgcn_s_setprio(1);
        #pragma unroll
        for (int ss = 0; ss < 4; ++ss) {
            short8 vf0 = *(const short8*)&Vs[sl][ss*512 + lane*8];
            short8 vf1 = *(const short8*)&Vs[sl][(4+ss)*512 + lane*8];
            ctx0 = mfma32(pa.p[ss], vf0, ctx0);
            ctx1 = mfma32(pa.p[ss], vf1, ctx1);
        }
        __builtin_amdgcn_s_setprio(0);
    }

    // unnormalized partial epilogue
    const size_t prow = ((size_t)kz*32 + bh)*SEQ + q0;
    #pragma unroll
    for (int r = 0; r < 16; ++r) {
        const int qrow = (r&3) + 8*(r>>2) + 4*h;
        unsigned short* p = &Pc[(prow + qrow)*64 + l31];
        p[0]  = bf16rne(ctx0[r]);
        p[32] = bf16rne(ctx1[r]);
    }
    if (lane < 32)
        Pl[(size_t)kz*(32*SEQ) + (size_t)bh*SEQ + q0 + l31] = lsum;
}

// ---------------- combine: Cb = (Pc0 + Pc1) / (Pl0 + Pl1), bf16 out ----------------
__global__ __launch_bounds__(256)
void combine(const unsigned short* __restrict__ Pc, const float* __restrict__ Pl,
             unsigned short* __restrict__ Cb)
{
    const int i = blockIdx.x*256 + threadIdx.x;   // 524288 threads
    const int row = i >> 3;                        // bh*SEQ + s  (65536 rows)
    const int dc = (i & 7) * 8;
    const float inv = 1.0f / (Pl[row] + Pl[32*SEQ + row]);
    short8 a = *(const short8*)&Pc[(size_t)row*64 + dc];
    short8 c = *(const short8*)&Pc[((size_t)32*SEQ + row)*64 + dc];
    const int bh = row >> 11, s = row & (SEQ-1);
    unsigned short* o = &Cb[((size_t)(bh>>4)*SEQ + s)*DIM + (bh&15)*HDIM + dc];
    uint4 w;
    float v0 = (bf2f((unsigned short)a[0]) + bf2f((unsigned short)c[0]))*inv;
    float v1 = (bf2f((unsigned short)a[1]) + bf2f((unsigned short)c[1]))*inv;
    float v2 = (bf2f((unsigned short)a[2]) + bf2f((unsigned short)c[2]))*inv;
    float v3 = (bf2f((unsigned short)a[3]) + bf2f((unsigned short)c[3]))*inv;
    float v4 = (bf2f((unsigned short)a[4]) + bf2f((unsigned short)c[4]))*inv;
    float v5 = (bf2f((unsigned short)a[5]) + bf2f((unsigned short)c[5]))*inv;
    float v6 = (bf2f((unsigned short)a[6]) + bf2f((unsigned short)c[6]))*inv;
    float v7 = (bf2f((unsigned short)a[7]) + bf2f((unsigned short)c[7]))*inv;
    w.x = (unsigned)bf16rne(v0) | ((unsigned)bf16rne(v1) << 16);
    w.y = (unsigned)bf16rne(v2) | ((unsigned)bf16rne(v3) << 16);
    w.z = (unsigned)bf16rne(v4) | ((unsigned)bf16rne(v5) << 16);
    w.w = (unsigned)bf16rne(v6) | ((unsigned)bf16rne(v7) << 16);
    *(uint4*)o = w;
}

extern "C" void kernel_launch(void* const* d_in, const int* in_sizes, int n_in,
                              void* d_out, int out_size, void* d_ws, size_t ws_size,
                              hipStream_t stream) {
    const float* x  = (const float*)d_in[0];
    const float* wq = (const float*)d_in[1];
    const float* bq = (const float*)d_in[2];
    const float* wk = (const float*)d_in[3];
    const float* bk = (const float*)d_in[4];
    const float* wv = (const float*)d_in[5];
    const float* bv = (const float*)d_in[6];
    const float* wo = (const float*)d_in[7];
    const float* bo = (const float*)d_in[8];
    float* out = (float*)d_out;

    // ws (ushort offsets, 48 MB total):
    //   [0,8M)   Xb      -> Kpb after gemm_qkv (x dead)
    //   [8,16M)  Wq|Wk|Wv|Wo ; Pl aliases Wq region after gemm_qkv (dead)
    //   [16,24M) Qb      -> Cb after attn (Q dead)
    //   [24,40M) Kb|Vb   -> Pc after pack_kv (raw K/V dead)
    //   [40,48M) Vpb
    unsigned short* Xb  = (unsigned short*)d_ws;
    unsigned short* Wqb = Xb  + XN;
    unsigned short* Wkb = Wqb + WN;
    unsigned short* Wvb = Wkb + WN;
    unsigned short* Wob = Wvb + WN;
    unsigned short* Qb  = Wob + WN;
    unsigned short* Kb  = Qb  + XN;
    unsigned short* Vb  = Kb  + XN;
    unsigned short* Vpb = Vb  + XN;
    unsigned short* Kpb = Xb;
    unsigned short* Pc  = Kb;            // 16 MB: 2 x 65536 x 64 bf16
    float*          Pl  = (float*)Wqb;   // 512 KB: 2 x 65536 f32
    unsigned short* Cb  = Qb;

    prep<<<4096, 256, 0, stream>>>(x, wq, wk, wv, wo, Xb);

    gemm_qkv<<<dim3(24, 32), 256, 0, stream>>>(Xb, Wqb, Wkb, Wvb, bq, bk, bv, Qb, Kb, Vb);

    pack_kv<<<dim3(SEQ/64, BATCH*NHEADS, 2), 256, 0, stream>>>(Kb, Vb, Kpb, Vpb);

    attn_ks<<<dim3(16, BATCH*NHEADS, 2), 256, 0, stream>>>(Qb, Kpb, Vpb, Pc, Pl);

    combine<<<2048, 256, 0, stream>>>(Pc, Pl, Cb);

    gemm_o<<<dim3(8, 64), 256, 0, stream>>>(Cb, Wob, bo, out);
}

// Round 13
// 140.316 us; speedup vs baseline: 1.0635x; 1.0635x over previous
//
#include <hip/hip_runtime.h>

#define DIM 1024
#define NHEADS 16
#define HDIM 64
#define BATCH 2
#define SEQ 2048
#define MTOT (BATCH*SEQ)
// 1/sqrt(64) * log2(e), folded into Q so softmax uses exp2
#define QSCALE 0.18033688011112042f
#define XN ((size_t)MTOT*DIM)
#define WN ((size_t)DIM*DIM)

typedef __attribute__((ext_vector_type(8))) short short8;
typedef __attribute__((ext_vector_type(4))) float f32x4;
typedef __attribute__((ext_vector_type(16))) float f32x16;
typedef __attribute__((ext_vector_type(2))) int int2v;

static __device__ __forceinline__ unsigned short bf16rne(float f) {
    unsigned u = __builtin_bit_cast(unsigned, f);
    return (unsigned short)((u + 0x7fffu + ((u >> 16) & 1u)) >> 16);
}

// async global->LDS, 16B per lane; LDS dest must be wave-uniform (HW adds lane*16).
static __device__ __forceinline__ void gld16(const void* g, void* l) {
    __builtin_amdgcn_global_load_lds((const __attribute__((address_space(1))) void*)g,
                                     (__attribute__((address_space(3))) void*)l, 16, 0, 0);
}

static __device__ __forceinline__ f32x16 mfma32(short8 a, short8 b, f32x16 c) {
    return __builtin_amdgcn_mfma_f32_32x32x16_bf16(a, b, c, 0, 0, 0);
}

// ---------------- fused f32 -> bf16 convert of x + 4 weights ----------------
__global__ __launch_bounds__(256)
void prep(const float* __restrict__ x, const float* __restrict__ wq, const float* __restrict__ wk,
          const float* __restrict__ wv, const float* __restrict__ wo, unsigned short* __restrict__ dst)
{
    const size_t i = ((size_t)blockIdx.x*256 + threadIdx.x)*8;
    const float* s; size_t o;
    if (i < XN)           { s = x;  o = i; }
    else if (i < XN+WN)   { s = wq; o = i - XN; }
    else if (i < XN+2*WN) { s = wk; o = i - XN - WN; }
    else if (i < XN+3*WN) { s = wv; o = i - XN - 2*WN; }
    else                  { s = wo; o = i - XN - 3*WN; }
    float4 a = *(const float4*)(s + o);
    float4 b = *(const float4*)(s + o + 4);
    uint4 w;
    w.x = (unsigned)bf16rne(a.x) | ((unsigned)bf16rne(a.y) << 16);
    w.y = (unsigned)bf16rne(a.z) | ((unsigned)bf16rne(a.w) << 16);
    w.z = (unsigned)bf16rne(b.x) | ((unsigned)bf16rne(b.y) << 16);
    w.w = (unsigned)bf16rne(b.z) | ((unsigned)bf16rne(b.w) << 16);
    *(uint4*)&dst[i] = w;
}

// ---------------- fused QKV bf16 GEMM: 8 waves, wave-tile 64x32, 16 waves/CU ----------------
// 128x128 tile, BK=32, 512 thr. Per wave-iter: 1 A + 1 B gld16, 6 ds_read_b128, 8 MFMA
// (half the r11 per-wave chain). 4-slot LDS ring (64KB -> 2 blocks/CU = 16 waves/CU),
// depth-2 prefetch, counted s_waitcnt vmcnt(2) (2 loads/stage), raw barrier.
__global__ __launch_bounds__(512)
void gemm_qkv(const unsigned short* __restrict__ A,
              const unsigned short* __restrict__ W0, const unsigned short* __restrict__ W1,
              const unsigned short* __restrict__ W2,
              const float* __restrict__ b0, const float* __restrict__ b1, const float* __restrict__ b2,
              unsigned short* __restrict__ o0, unsigned short* __restrict__ o1, unsigned short* __restrict__ o2)
{
    __shared__ __align__(16) unsigned short As[4][4096];
    __shared__ __align__(16) unsigned short Bs[4][4096];
    const int t = threadIdx.x, wid = t >> 6, lane = t & 63;
    const int lr = lane & 15, lg = lane >> 4;
    // XCD swizzle: 768 blocks, XCD c gets 4 consecutive m-panels + all W
    const int bid = blockIdx.y * 24 + blockIdx.x;
    const int swz = (bid & 7) * 96 + (bid >> 3);
    const int sx = swz % 24, sy = swz / 24;
    const int widx = sx >> 3;
    const int n0 = (sx & 7) << 7;
    const int m0 = sy << 7;
    const unsigned short* W = widx == 0 ? W0 : (widx == 1 ? W1 : W2);
    const float* bias        = widx == 0 ? b0 : (widx == 1 ? b1 : b2);
    const float scale        = widx == 0 ? QSCALE : 1.0f;
    unsigned short* out      = widx == 0 ? o0 : (widx == 1 ? o1 : o2);

    const int wm = wid >> 2, wn = wid & 3;   // wave tile: rows wm*64, cols wn*32
    const unsigned short* Ag = A + (size_t)(m0 + wid*16 + lr)*DIM + lg*8;
    const unsigned short* Bg = W + (size_t)(n0 + wid*16 + lr)*DIM + lg*8;

    auto stage = [&](int tt, int slot) {   // 2 gld16/wave: A-frag[wid], B-frag[wid]
        const int ko = tt * 32;
        gld16(Ag + ko, &As[slot][wid*512]);
        gld16(Bg + ko, &Bs[slot][wid*512]);
    };

    f32x4 acc[4][2] = {};
    stage(0, 0); stage(1, 1);   // 4 loads in flight

    for (int it = 0; it < DIM/32; ++it) {
        // drain own stage(it) (2 loads); stage(it+1) stays in flight
        if (it < DIM/32 - 1) { asm volatile("s_waitcnt vmcnt(2)" ::: "memory"); }
        else                 { asm volatile("s_waitcnt vmcnt(0)" ::: "memory"); }
        __builtin_amdgcn_s_barrier();   // all waves' slot-it frags landed
        const int cb = it & 3;
        short8 af[4], bf[2];
        #pragma unroll
        for (int i = 0; i < 4; ++i) af[i] = *(const short8*)&As[cb][(wm*4+i)*512 + lane*8];
        #pragma unroll
        for (int i = 0; i < 2; ++i) bf[i] = *(const short8*)&Bs[cb][(wn*2+i)*512 + lane*8];
        if (it + 2 < DIM/32) stage(it + 2, (it + 2) & 3);   // slot read 2 barriers ago
        __builtin_amdgcn_s_setprio(1);
        #pragma unroll
        for (int mb = 0; mb < 4; ++mb)
            #pragma unroll
            for (int nb = 0; nb < 2; ++nb)
                acc[mb][nb] = __builtin_amdgcn_mfma_f32_16x16x32_bf16(af[mb], bf[nb], acc[mb][nb], 0, 0, 0);
        __builtin_amdgcn_s_setprio(0);
    }

    #pragma unroll
    for (int nb = 0; nb < 2; ++nb) {
        const int col = n0 + wn*32 + nb*16 + lr;
        const float bv = bias[col];
        #pragma unroll
        for (int mb = 0; mb < 4; ++mb) {
            #pragma unroll
            for (int j = 0; j < 4; ++j) {
                const int row = m0 + wm*64 + mb*16 + lg*4 + j;
                out[(size_t)row*DIM + col] = bf16rne((acc[mb][nb][j] + bv) * scale);
            }
        }
    }
}

// ---------------- O-projection GEMM: 64x128 tile, counted-vmcnt, f32 out ----------------
__global__ __launch_bounds__(256)
void gemm_o(const unsigned short* __restrict__ A, const unsigned short* __restrict__ W,
            const float* __restrict__ bias, float* __restrict__ fo)
{
    __shared__ __align__(16) unsigned short As[3][2048];
    __shared__ __align__(16) unsigned short Bs[3][4096];
    const int t = threadIdx.x, wid = t >> 6, lane = t & 63;
    const int lr = lane & 15, lg = lane >> 4;
    const int bid = blockIdx.y * 8 + blockIdx.x;
    const int swz = (bid & 7) * 64 + (bid >> 3);
    const int n0 = (swz & 7) << 7;
    const int m0 = (swz >> 3) << 6;
    const int wm = wid >> 1, wn = wid & 1;

    const int fa = wid;
    const int g0 = 2*wid, g1 = g0 + 1;
    const unsigned short* Ag  = A + (size_t)(m0 + fa*16 + lr)*DIM + lg*8;
    const unsigned short* Bg0 = W + (size_t)(n0 + g0*16 + lr)*DIM + lg*8;
    const unsigned short* Bg1 = W + (size_t)(n0 + g1*16 + lr)*DIM + lg*8;

    auto stage = [&](int tt, int slot) {
        const int ko = tt * 32;
        gld16(Ag + ko, &As[slot][fa*512]);
        gld16(Bg0 + ko, &Bs[slot][g0*512]); gld16(Bg1 + ko, &Bs[slot][g1*512]);
    };

    f32x4 acc[2][4] = {};
    stage(0, 0); stage(1, 1);
    int c0 = 0, c1 = 1, c2 = 2;

    for (int it = 0; it < DIM/32; ++it) {
        if (it < DIM/32 - 2) { asm volatile("s_waitcnt vmcnt(3)" ::: "memory"); }
        else                 { asm volatile("s_waitcnt vmcnt(0)" ::: "memory"); }
        __builtin_amdgcn_s_barrier();
        short8 af[2], bf[4];
        #pragma unroll
        for (int i = 0; i < 2; ++i) af[i] = *(const short8*)&As[c0][(wm*2+i)*512 + lane*8];
        #pragma unroll
        for (int i = 0; i < 4; ++i) bf[i] = *(const short8*)&Bs[c0][(wn*4+i)*512 + lane*8];
        if (it + 2 < DIM/32) stage(it + 2, c2);
        __builtin_amdgcn_s_setprio(1);
        #pragma unroll
        for (int mb = 0; mb < 2; ++mb)
            #pragma unroll
            for (int nb = 0; nb < 4; ++nb)
                acc[mb][nb] = __builtin_amdgcn_mfma_f32_16x16x32_bf16(af[mb], bf[nb], acc[mb][nb], 0, 0, 0);
        __builtin_amdgcn_s_setprio(0);
        const int tmp = c0; c0 = c1; c1 = c2; c2 = tmp;
    }

    #pragma unroll
    for (int nb = 0; nb < 4; ++nb) {
        const int col = n0 + wn*64 + nb*16 + lr;
        const float bv = bias[col];
        #pragma unroll
        for (int mb = 0; mb < 2; ++mb) {
            #pragma unroll
            for (int j = 0; j < 4; ++j) {
                const int row = m0 + wm*32 + mb*16 + lg*4 + j;
                fo[(size_t)row*DIM + col] = acc[mb][nb][j] + bv;
            }
        }
    }
}

// ---------------- K/V pack: row-major -> attention-fragment-linear ----------------
__global__ __launch_bounds__(256)
void pack_kv(const unsigned short* __restrict__ Kg, const unsigned short* __restrict__ V,
             unsigned short* __restrict__ Kp, unsigned short* __restrict__ Vp)
{
    __shared__ unsigned short tile[64][66];
    const int t  = threadIdx.x;
    const int st = blockIdx.x;
    const int bh = blockIdx.y;
    const int isV = blockIdx.z;
    const int b = bh >> 4, h = bh & 15;
    const unsigned short* src = isV ? V : Kg;
    unsigned short* dstb = (isV ? Vp : Kp) + ((size_t)bh*32 + st)*4096;
    const int sr = t >> 3;
    const int dc = (t & 7) * 8;

    #pragma unroll
    for (int r = 0; r < 2; ++r) {
        const int s = r*32 + sr;
        short8 v = *(const short8*)(src + (size_t)(b*SEQ + st*64 + s)*DIM + h*HDIM + dc);
        #pragma unroll
        for (int e = 0; e < 8; ++e) tile[s][dc + e] = (unsigned short)v[e];
    }
    __syncthreads();
    #pragma unroll
    for (int r = 0; r < 2; ++r) {
        const int idx = t + r*256;
        const int fr = idx >> 6, ln = idx & 63;
        short8 ov;
        if (isV) {
            const int s0 = (fr & 3)*16 + (ln >> 5)*8;
            const int d  = (fr >> 2)*32 + (ln & 31);
            #pragma unroll
            for (int e = 0; e < 8; ++e) ov[e] = (short)tile[s0 + e][d];
        } else {
            const int key = (fr >> 2)*32 + (ln & 31);
            const int d0  = (fr & 3)*16 + (ln >> 5)*8;
            #pragma unroll
            for (int e = 0; e < 8; ++e) ov[e] = (short)tile[key][d0 + e];
        }
        *(short8*)(dstb + fr*512 + ln*8) = ov;
    }
}

// ---------------- MFMA flash attention, 2-tile pipelined, counted vmcnt (r11-proven) ----------------
struct PA { short8 p[4]; };

static __device__ __forceinline__ PA softmax_pack(const f32x16& s0, const f32x16& s1, float& lsum) {
    float rsum = 0.f;
    unsigned pw0[4][2], pw1[4][2];
    #pragma unroll
    for (int r1 = 0; r1 < 4; ++r1)
        #pragma unroll
        for (int tt = 0; tt < 2; ++tt) {
            float pa_ = __builtin_amdgcn_exp2f(s0[4*r1+2*tt]);
            float pb_ = __builtin_amdgcn_exp2f(s0[4*r1+2*tt+1]);
            float pc_ = __builtin_amdgcn_exp2f(s1[4*r1+2*tt]);
            float pd_ = __builtin_amdgcn_exp2f(s1[4*r1+2*tt+1]);
            rsum += (pa_ + pb_) + (pc_ + pd_);
            asm("v_cvt_pk_bf16_f32 %0, %1, %2" : "=v"(pw0[r1][tt]) : "v"(pa_), "v"(pb_));
            asm("v_cvt_pk_bf16_f32 %0, %1, %2" : "=v"(pw1[r1][tt]) : "v"(pc_), "v"(pd_));
        }
    rsum += __shfl_xor(rsum, 32);
    lsum += rsum;
    PA r;
    #pragma unroll
    for (int ss = 0; ss < 4; ++ss) {
        union { short8 s8; unsigned u[4]; } pu;
        #pragma unroll
        for (int tt = 0; tt < 2; ++tt) {
            const unsigned a = (ss >> 1) ? pw1[2*(ss&1)][tt]   : pw0[2*(ss&1)][tt];
            const unsigned b = (ss >> 1) ? pw1[2*(ss&1)+1][tt] : pw0[2*(ss&1)+1][tt];
            int2v sw = __builtin_amdgcn_permlane32_swap((int)a, (int)b, false, false);
            pu.u[tt]     = (unsigned)sw[0];
            pu.u[2 + tt] = (unsigned)sw[1];
        }
        r.p[ss] = pu.s8;
    }
    return r;
}

__global__ __launch_bounds__(256)
void attn_mfma2(const unsigned short* __restrict__ Q, const unsigned short* __restrict__ Kp,
                const unsigned short* __restrict__ Vp, unsigned short* __restrict__ O)
{
    __shared__ __align__(16) unsigned short Ks[4][4096];
    __shared__ __align__(16) unsigned short Vs[4][4096];
    const int t = threadIdx.x, wid = t >> 6, lane = t & 63;
    const int l31 = lane & 31, h = lane >> 5;
    const int bid = blockIdx.y * 16 + blockIdx.x;
    const int swz = (bid & 7) * 64 + (bid >> 3);
    const int qt = swz & 15, bh = swz >> 4;
    const int b = bh >> 4, hh = bh & 15;
    const size_t qkbase = (size_t)b*SEQ*DIM + (size_t)hh*HDIM;
    const unsigned short* Qb = Q + qkbase;
    unsigned short*       Ob = O + qkbase;
    const int q0 = qt*128 + wid*32;

    short8 qf[4];
    #pragma unroll
    for (int ds = 0; ds < 4; ++ds)
        qf[ds] = *(const short8*)&Qb[(size_t)(q0 + l31)*DIM + ds*16 + h*8];

    const int f0 = 2*wid, f1 = f0 + 1;
    const unsigned short* Kg0 = Kp + (size_t)bh*32*4096 + f0*512 + lane*8;
    const unsigned short* Kg1 = Kg0 + 512;
    const unsigned short* Vg0 = Vp + (size_t)bh*32*4096 + f0*512 + lane*8;
    const unsigned short* Vg1 = Vg0 + 512;

    auto stage = [&](int tn) {
        const size_t ko = (size_t)tn * 4096;
        const int bb = tn & 3;
        gld16(Kg0 + ko, &Ks[bb][f0*512]); gld16(Kg1 + ko, &Ks[bb][f1*512]);
        gld16(Vg0 + ko, &Vs[bb][f0*512]); gld16(Vg1 + ko, &Vs[bb][f1*512]);
    };

    f32x16 ctx0 = {}, ctx1 = {};
    float lsum = 0.0f;

    stage(0); stage(1);

    const int NW = SEQ/128;
    for (int w = 0; w < NW; ++w) {
        const int t0 = 2*w;
        const int ba = t0 & 3, bb2 = (t0+1) & 3;
        const bool more = (w + 1 < NW);

        if (more) { asm volatile("s_waitcnt vmcnt(4)" ::: "memory"); }
        else      { asm volatile("s_waitcnt vmcnt(0)" ::: "memory"); }
        __builtin_amdgcn_s_barrier();
        if (more) stage(t0 + 2);

        f32x16 s0a = {}, s1a = {};
        __builtin_amdgcn_s_setprio(1);
        #pragma unroll
        for (int ds = 0; ds < 4; ++ds) {
            short8 kf0 = *(const short8*)&Ks[ba][ds*512 + lane*8];
            short8 kf1 = *(const short8*)&Ks[ba][(4+ds)*512 + lane*8];
            s0a = mfma32(kf0, qf[ds], s0a);
            s1a = mfma32(kf1, qf[ds], s1a);
        }
        __builtin_amdgcn_s_setprio(0);

        PA pa = softmax_pack(s0a, s1a, lsum);

        if (more) { asm volatile("s_waitcnt vmcnt(4)" ::: "memory"); }
        else      { asm volatile("s_waitcnt vmcnt(0)" ::: "memory"); }
        __builtin_amdgcn_s_barrier();
        if (more) stage(t0 + 3);

        f32x16 s0b = {}, s1b = {};
        __builtin_amdgcn_s_setprio(1);
        #pragma unroll
        for (int ds = 0; ds < 4; ++ds) {
            short8 kf0 = *(const short8*)&Ks[bb2][ds*512 + lane*8];
            short8 kf1 = *(const short8*)&Ks[bb2][(4+ds)*512 + lane*8];
            s0b = mfma32(kf0, qf[ds], s0b);
            s1b = mfma32(kf1, qf[ds], s1b);
        }
        #pragma unroll
        for (int ss = 0; ss < 4; ++ss) {
            short8 vf0 = *(const short8*)&Vs[ba][ss*512 + lane*8];
            short8 vf1 = *(const short8*)&Vs[ba][(4+ss)*512 + lane*8];
            ctx0 = mfma32(pa.p[ss], vf0, ctx0);
            ctx1 = mfma32(pa.p[ss], vf1, ctx1);
        }
        __builtin_amdgcn_s_setprio(0);

        PA pb = softmax_pack(s0b, s1b, lsum);

        __builtin_amdgcn_s_setprio(1);
        #pragma unroll
        for (int ss = 0; ss < 4; ++ss) {
            short8 vf0 = *(const short8*)&Vs[bb2][ss*512 + lane*8];
            short8 vf1 = *(const short8*)&Vs[bb2][(4+ss)*512 + lane*8];
            ctx0 = mfma32(pb.p[ss], vf0, ctx0);
            ctx1 = mfma32(pb.p[ss], vf1, ctx1);
        }
        __builtin_amdgcn_s_setprio(0);
    }

    const float linv = 1.0f / lsum;
    #pragma unroll
    for (int r = 0; r < 16; ++r) {
        const int qrow = (r&3) + 8*(r>>2) + 4*h;
        const float nm = __shfl(linv, qrow);
        unsigned short* p = &Ob[(size_t)(q0 + qrow)*DIM + l31];
        p[0]  = bf16rne(ctx0[r] * nm);
        p[32] = bf16rne(ctx1[r] * nm);
    }
}

extern "C" void kernel_launch(void* const* d_in, const int* in_sizes, int n_in,
                              void* d_out, int out_size, void* d_ws, size_t ws_size,
                              hipStream_t stream) {
    const float* x  = (const float*)d_in[0];
    const float* wq = (const float*)d_in[1];
    const float* bq = (const float*)d_in[2];
    const float* wk = (const float*)d_in[3];
    const float* bk = (const float*)d_in[4];
    const float* wv = (const float*)d_in[5];
    const float* bv = (const float*)d_in[6];
    const float* wo = (const float*)d_in[7];
    const float* bo = (const float*)d_in[8];
    float* out = (float*)d_out;

    // ws (ushort): Xb 4M | Wq 1M | Wk 1M | Wv 1M | Wo 1M | Qb 4M | Kb 4M | Vb 4M | Vpb 4M = 48 MB
    // Kpb aliases Xb (x dead after QKV GEMM); Cb aliases Vb (raw V dead after pack_kv).
    unsigned short* Xb  = (unsigned short*)d_ws;
    unsigned short* Wqb = Xb  + XN;
    unsigned short* Wkb = Wqb + WN;
    unsigned short* Wvb = Wkb + WN;
    unsigned short* Wob = Wvb + WN;
    unsigned short* Qb  = Wob + WN;
    unsigned short* Kb  = Qb  + XN;
    unsigned short* Vb  = Kb  + XN;
    unsigned short* Vpb = Vb  + XN;
    unsigned short* Kpb = Xb;
    unsigned short* Cb  = Vb;

    prep<<<4096, 256, 0, stream>>>(x, wq, wk, wv, wo, Xb);

    gemm_qkv<<<dim3(24, 32), 512, 0, stream>>>(Xb, Wqb, Wkb, Wvb, bq, bk, bv, Qb, Kb, Vb);

    pack_kv<<<dim3(SEQ/64, BATCH*NHEADS, 2), 256, 0, stream>>>(Kb, Vb, Kpb, Vpb);
    attn_mfma2<<<dim3(SEQ/128, BATCH*NHEADS), 256, 0, stream>>>(Qb, Kpb, Vpb, Cb);

    gemm_o<<<dim3(8, 64), 256, 0, stream>>>(Cb, Wob, bo, out);
}

// Round 14
// 133.204 us; speedup vs baseline: 1.1203x; 1.0534x over previous
//
#include <hip/hip_runtime.h>

#define DIM 1024
#define NHEADS 16
#define HDIM 64
#define BATCH 2
#define SEQ 2048
#define MTOT (BATCH*SEQ)
// 1/sqrt(64) * log2(e), folded into Q so softmax uses exp2
#define QSCALE 0.18033688011112042f
#define XN ((size_t)MTOT*DIM)
#define WN ((size_t)DIM*DIM)

typedef __attribute__((ext_vector_type(8))) short short8;
typedef __attribute__((ext_vector_type(4))) float f32x4;
typedef __attribute__((ext_vector_type(16))) float f32x16;
typedef __attribute__((ext_vector_type(2))) int int2v;

static __device__ __forceinline__ unsigned short bf16rne(float f) {
    unsigned u = __builtin_bit_cast(unsigned, f);
    return (unsigned short)((u + 0x7fffu + ((u >> 16) & 1u)) >> 16);
}

// async global->LDS, 16B per lane; LDS dest must be wave-uniform (HW adds lane*16).
static __device__ __forceinline__ void gld16(const void* g, void* l) {
    __builtin_amdgcn_global_load_lds((const __attribute__((address_space(1))) void*)g,
                                     (__attribute__((address_space(3))) void*)l, 16, 0, 0);
}

static __device__ __forceinline__ f32x16 mfma32(short8 a, short8 b, f32x16 c) {
    return __builtin_amdgcn_mfma_f32_32x32x16_bf16(a, b, c, 0, 0, 0);
}

// ---------------- fused f32 -> bf16 convert of x + 4 weights ----------------
__global__ __launch_bounds__(256)
void prep(const float* __restrict__ x, const float* __restrict__ wq, const float* __restrict__ wk,
          const float* __restrict__ wv, const float* __restrict__ wo, unsigned short* __restrict__ dst)
{
    const size_t i = ((size_t)blockIdx.x*256 + threadIdx.x)*8;
    const float* s; size_t o;
    if (i < XN)           { s = x;  o = i; }
    else if (i < XN+WN)   { s = wq; o = i - XN; }
    else if (i < XN+2*WN) { s = wk; o = i - XN - WN; }
    else if (i < XN+3*WN) { s = wv; o = i - XN - 2*WN; }
    else                  { s = wo; o = i - XN - 3*WN; }
    float4 a = *(const float4*)(s + o);
    float4 b = *(const float4*)(s + o + 4);
    uint4 w;
    w.x = (unsigned)bf16rne(a.x) | ((unsigned)bf16rne(a.y) << 16);
    w.y = (unsigned)bf16rne(a.z) | ((unsigned)bf16rne(a.w) << 16);
    w.z = (unsigned)bf16rne(b.x) | ((unsigned)bf16rne(b.y) << 16);
    w.w = (unsigned)bf16rne(b.z) | ((unsigned)bf16rne(b.w) << 16);
    *(uint4*)&dst[i] = w;
}

// ---------------- fused QKV bf16 GEMM, counted-vmcnt pipeline, 3 blocks/CU ----------------
// 128x128 tile, BK=32, 256 thr (4 waves 2x2), wave tile 64x64. r11-proven main loop.
// Q (widx==0): row-major epilogue. K/V (widx==1/2): one-shot LDS-repack epilogue ->
// attention-fragment-linear Kp/Vp with CONTIGUOUS global stores (pack_kv fused away;
// global-scatter epilogues proven bad in r6/r10, LDS repack keeps stores coalesced).
__global__ __launch_bounds__(256)
void gemm_qkv(const unsigned short* __restrict__ A,
              const unsigned short* __restrict__ W0, const unsigned short* __restrict__ W1,
              const unsigned short* __restrict__ W2,
              const float* __restrict__ b0, const float* __restrict__ b1, const float* __restrict__ b2,
              unsigned short* __restrict__ o0, unsigned short* __restrict__ o1, unsigned short* __restrict__ o2)
{
    __shared__ __align__(16) unsigned short smem[24576];   // 48 KB: As[3]|Bs[3] ring; epilogue tile
    #define AS(s) (smem + (s)*4096)
    #define BS(s) (smem + 12288 + (s)*4096)
    const int t = threadIdx.x, wid = t >> 6, lane = t & 63;
    const int lr = lane & 15, lg = lane >> 4;
    const int bid = blockIdx.y * 24 + blockIdx.x;
    const int swz = (bid & 7) * 96 + (bid >> 3);
    const int sx = swz % 24, sy = swz / 24;
    const int widx = sx >> 3;
    const int n0 = (sx & 7) << 7;
    const int m0 = sy << 7;
    const unsigned short* W = widx == 0 ? W0 : (widx == 1 ? W1 : W2);
    const float* bias        = widx == 0 ? b0 : (widx == 1 ? b1 : b2);

    const int wm = wid >> 1, wn = wid & 1;
    const int f0 = 2*wid, f1 = f0 + 1;
    const unsigned short* Ag0 = A + (size_t)(m0 + f0*16 + lr)*DIM + lg*8;
    const unsigned short* Ag1 = A + (size_t)(m0 + f1*16 + lr)*DIM + lg*8;
    const unsigned short* Bg0 = W + (size_t)(n0 + f0*16 + lr)*DIM + lg*8;
    const unsigned short* Bg1 = W + (size_t)(n0 + f1*16 + lr)*DIM + lg*8;

    auto stage = [&](int tt, int slot) {
        const int ko = tt * 32;
        gld16(Ag0 + ko, AS(slot) + f0*512); gld16(Ag1 + ko, AS(slot) + f1*512);
        gld16(Bg0 + ko, BS(slot) + f0*512); gld16(Bg1 + ko, BS(slot) + f1*512);
    };

    f32x4 acc[4][4] = {};
    stage(0, 0); stage(1, 1);
    int c0 = 0, c1 = 1, c2 = 2;

    for (int it = 0; it < DIM/32; ++it) {
        if (it < DIM/32 - 2) { asm volatile("s_waitcnt vmcnt(4)" ::: "memory"); }
        else                 { asm volatile("s_waitcnt vmcnt(0)" ::: "memory"); }
        __builtin_amdgcn_s_barrier();
        short8 af[4], bf[4];
        #pragma unroll
        for (int i = 0; i < 4; ++i) af[i] = *(const short8*)(AS(c0) + (wm*4+i)*512 + lane*8);
        #pragma unroll
        for (int i = 0; i < 4; ++i) bf[i] = *(const short8*)(BS(c0) + (wn*4+i)*512 + lane*8);
        if (it + 2 < DIM/32) stage(it + 2, c2);
        __builtin_amdgcn_s_setprio(1);
        #pragma unroll
        for (int mb = 0; mb < 4; ++mb)
            #pragma unroll
            for (int nb = 0; nb < 4; ++nb)
                acc[mb][nb] = __builtin_amdgcn_mfma_f32_16x16x32_bf16(af[mb], bf[nb], acc[mb][nb], 0, 0, 0);
        __builtin_amdgcn_s_setprio(0);
        const int tmp = c0; c0 = c1; c1 = c2; c2 = tmp;
    }

    if (widx == 0) {
        // Q: row-major, pre-scaled by QSCALE
        #pragma unroll
        for (int nb = 0; nb < 4; ++nb) {
            const int col = n0 + wn*64 + nb*16 + lr;
            const float bv = bias[col];
            #pragma unroll
            for (int mb = 0; mb < 4; ++mb) {
                #pragma unroll
                for (int j = 0; j < 4; ++j) {
                    const int row = m0 + wm*64 + mb*16 + lg*4 + j;
                    o0[(size_t)row*DIM + col] = bf16rne((acc[mb][nb][j] + bv) * QSCALE);
                }
            }
        }
    } else {
        // K/V: acc -> LDS tile[128][136] (pad 136 -> 16B-aligned rows), then repack to
        // fragment-linear with contiguous stores. Values bit-identical to pack_kv path.
        unsigned short* outp = (widx == 1) ? o1 : o2;
        const int isV = (widx == 2);
        __syncthreads();   // all K-loop LDS reads done before tile overwrite
        unsigned short (*tile)[136] = (unsigned short (*)[136])smem;
        #pragma unroll
        for (int nb = 0; nb < 4; ++nb) {
            const int col = wn*64 + nb*16 + lr;
            const float bv = bias[n0 + col];
            #pragma unroll
            for (int mb = 0; mb < 4; ++mb) {
                #pragma unroll
                for (int j = 0; j < 4; ++j)
                    tile[wm*64 + mb*16 + lg*4 + j][col] = bf16rne(acc[mb][nb][j] + bv);
            }
        }
        __syncthreads();
        const int bb  = m0 >> 11;               // batch
        const int kt0 = (m0 & (SEQ-1)) >> 6;    // first of 2 key-tiles
        const int hh0 = n0 >> 6;                // first of 2 heads
        #pragma unroll
        for (int shot = 0; shot < 8; ++shot) {
            const int idx = t + shot*256;       // 0..2047 over 4 packed subtiles
            const int tid = idx >> 9;           // (hhl<<1)|ktl
            const int fr  = (idx >> 6) & 7;
            const int ln  = idx & 63;
            const int ktl = tid & 1, hhl = tid >> 1;
            short8 ov;
            if (isV) {
                const int r0 = ktl*64 + (fr & 3)*16 + (ln >> 5)*8;
                const int c  = hhl*64 + (fr >> 2)*32 + (ln & 31);
                #pragma unroll
                for (int e = 0; e < 8; ++e) ov[e] = (short)tile[r0 + e][c];
            } else {
                const int r  = ktl*64 + (fr >> 2)*32 + (ln & 31);
                const int cc = hhl*64 + (fr & 3)*16 + (ln >> 5)*8;
                ov = *(const short8*)&tile[r][cc];
            }
            unsigned short* dst = outp
                + ((size_t)((bb*NHEADS + hh0 + hhl)*32 + kt0 + ktl))*4096 + fr*512 + ln*8;
            *(short8*)dst = ov;
        }
    }
    #undef AS
    #undef BS
}

// ---------------- O-projection GEMM: 64x128 tile, counted-vmcnt, f32 out ----------------
__global__ __launch_bounds__(256)
void gemm_o(const unsigned short* __restrict__ A, const unsigned short* __restrict__ W,
            const float* __restrict__ bias, float* __restrict__ fo)
{
    __shared__ __align__(16) unsigned short As[3][2048];
    __shared__ __align__(16) unsigned short Bs[3][4096];
    const int t = threadIdx.x, wid = t >> 6, lane = t & 63;
    const int lr = lane & 15, lg = lane >> 4;
    const int bid = blockIdx.y * 8 + blockIdx.x;
    const int swz = (bid & 7) * 64 + (bid >> 3);
    const int n0 = (swz & 7) << 7;
    const int m0 = (swz >> 3) << 6;
    const int wm = wid >> 1, wn = wid & 1;

    const int fa = wid;
    const int g0 = 2*wid, g1 = g0 + 1;
    const unsigned short* Ag  = A + (size_t)(m0 + fa*16 + lr)*DIM + lg*8;
    const unsigned short* Bg0 = W + (size_t)(n0 + g0*16 + lr)*DIM + lg*8;
    const unsigned short* Bg1 = W + (size_t)(n0 + g1*16 + lr)*DIM + lg*8;

    auto stage = [&](int tt, int slot) {
        const int ko = tt * 32;
        gld16(Ag + ko, &As[slot][fa*512]);
        gld16(Bg0 + ko, &Bs[slot][g0*512]); gld16(Bg1 + ko, &Bs[slot][g1*512]);
    };

    f32x4 acc[2][4] = {};
    stage(0, 0); stage(1, 1);
    int c0 = 0, c1 = 1, c2 = 2;

    for (int it = 0; it < DIM/32; ++it) {
        if (it < DIM/32 - 2) { asm volatile("s_waitcnt vmcnt(3)" ::: "memory"); }
        else                 { asm volatile("s_waitcnt vmcnt(0)" ::: "memory"); }
        __builtin_amdgcn_s_barrier();
        short8 af[2], bf[4];
        #pragma unroll
        for (int i = 0; i < 2; ++i) af[i] = *(const short8*)&As[c0][(wm*2+i)*512 + lane*8];
        #pragma unroll
        for (int i = 0; i < 4; ++i) bf[i] = *(const short8*)&Bs[c0][(wn*4+i)*512 + lane*8];
        if (it + 2 < DIM/32) stage(it + 2, c2);
        __builtin_amdgcn_s_setprio(1);
        #pragma unroll
        for (int mb = 0; mb < 2; ++mb)
            #pragma unroll
            for (int nb = 0; nb < 4; ++nb)
                acc[mb][nb] = __builtin_amdgcn_mfma_f32_16x16x32_bf16(af[mb], bf[nb], acc[mb][nb], 0, 0, 0);
        __builtin_amdgcn_s_setprio(0);
        const int tmp = c0; c0 = c1; c1 = c2; c2 = tmp;
    }

    #pragma unroll
    for (int nb = 0; nb < 4; ++nb) {
        const int col = n0 + wn*64 + nb*16 + lr;
        const float bv = bias[col];
        #pragma unroll
        for (int mb = 0; mb < 2; ++mb) {
            #pragma unroll
            for (int j = 0; j < 4; ++j) {
                const int row = m0 + wm*32 + mb*16 + lg*4 + j;
                fo[(size_t)row*DIM + col] = acc[mb][nb][j] + bv;
            }
        }
    }
}

// ---------------- MFMA flash attention, 2-tile pipelined, counted vmcnt (r11-proven) ----------------
struct PA { short8 p[4]; };

static __device__ __forceinline__ PA softmax_pack(const f32x16& s0, const f32x16& s1, float& lsum) {
    float rsum = 0.f;
    unsigned pw0[4][2], pw1[4][2];
    #pragma unroll
    for (int r1 = 0; r1 < 4; ++r1)
        #pragma unroll
        for (int tt = 0; tt < 2; ++tt) {
            float pa_ = __builtin_amdgcn_exp2f(s0[4*r1+2*tt]);
            float pb_ = __builtin_amdgcn_exp2f(s0[4*r1+2*tt+1]);
            float pc_ = __builtin_amdgcn_exp2f(s1[4*r1+2*tt]);
            float pd_ = __builtin_amdgcn_exp2f(s1[4*r1+2*tt+1]);
            rsum += (pa_ + pb_) + (pc_ + pd_);
            asm("v_cvt_pk_bf16_f32 %0, %1, %2" : "=v"(pw0[r1][tt]) : "v"(pa_), "v"(pb_));
            asm("v_cvt_pk_bf16_f32 %0, %1, %2" : "=v"(pw1[r1][tt]) : "v"(pc_), "v"(pd_));
        }
    rsum += __shfl_xor(rsum, 32);
    lsum += rsum;
    PA r;
    #pragma unroll
    for (int ss = 0; ss < 4; ++ss) {
        union { short8 s8; unsigned u[4]; } pu;
        #pragma unroll
        for (int tt = 0; tt < 2; ++tt) {
            const unsigned a = (ss >> 1) ? pw1[2*(ss&1)][tt]   : pw0[2*(ss&1)][tt];
            const unsigned b = (ss >> 1) ? pw1[2*(ss&1)+1][tt] : pw0[2*(ss&1)+1][tt];
            int2v sw = __builtin_amdgcn_permlane32_swap((int)a, (int)b, false, false);
            pu.u[tt]     = (unsigned)sw[0];
            pu.u[2 + tt] = (unsigned)sw[1];
        }
        r.p[ss] = pu.s8;
    }
    return r;
}

__global__ __launch_bounds__(256)
void attn_mfma2(const unsigned short* __restrict__ Q, const unsigned short* __restrict__ Kp,
                const unsigned short* __restrict__ Vp, unsigned short* __restrict__ O)
{
    __shared__ __align__(16) unsigned short Ks[4][4096];
    __shared__ __align__(16) unsigned short Vs[4][4096];
    const int t = threadIdx.x, wid = t >> 6, lane = t & 63;
    const int l31 = lane & 31, h = lane >> 5;
    const int bid = blockIdx.y * 16 + blockIdx.x;
    const int swz = (bid & 7) * 64 + (bid >> 3);
    const int qt = swz & 15, bh = swz >> 4;
    const int b = bh >> 4, hh = bh & 15;
    const size_t qkbase = (size_t)b*SEQ*DIM + (size_t)hh*HDIM;
    const unsigned short* Qb = Q + qkbase;
    unsigned short*       Ob = O + qkbase;
    const int q0 = qt*128 + wid*32;

    short8 qf[4];
    #pragma unroll
    for (int ds = 0; ds < 4; ++ds)
        qf[ds] = *(const short8*)&Qb[(size_t)(q0 + l31)*DIM + ds*16 + h*8];

    const int f0 = 2*wid, f1 = f0 + 1;
    const unsigned short* Kg0 = Kp + (size_t)bh*32*4096 + f0*512 + lane*8;
    const unsigned short* Kg1 = Kg0 + 512;
    const unsigned short* Vg0 = Vp + (size_t)bh*32*4096 + f0*512 + lane*8;
    const unsigned short* Vg1 = Vg0 + 512;

    auto stage = [&](int tn) {
        const size_t ko = (size_t)tn * 4096;
        const int bb = tn & 3;
        gld16(Kg0 + ko, &Ks[bb][f0*512]); gld16(Kg1 + ko, &Ks[bb][f1*512]);
        gld16(Vg0 + ko, &Vs[bb][f0*512]); gld16(Vg1 + ko, &Vs[bb][f1*512]);
    };

    f32x16 ctx0 = {}, ctx1 = {};
    float lsum = 0.0f;

    stage(0); stage(1);

    const int NW = SEQ/128;
    for (int w = 0; w < NW; ++w) {
        const int t0 = 2*w;
        const int ba = t0 & 3, bb2 = (t0+1) & 3;
        const bool more = (w + 1 < NW);

        if (more) { asm volatile("s_waitcnt vmcnt(4)" ::: "memory"); }
        else      { asm volatile("s_waitcnt vmcnt(0)" ::: "memory"); }
        __builtin_amdgcn_s_barrier();
        if (more) stage(t0 + 2);

        f32x16 s0a = {}, s1a = {};
        __builtin_amdgcn_s_setprio(1);
        #pragma unroll
        for (int ds = 0; ds < 4; ++ds) {
            short8 kf0 = *(const short8*)&Ks[ba][ds*512 + lane*8];
            short8 kf1 = *(const short8*)&Ks[ba][(4+ds)*512 + lane*8];
            s0a = mfma32(kf0, qf[ds], s0a);
            s1a = mfma32(kf1, qf[ds], s1a);
        }
        __builtin_amdgcn_s_setprio(0);

        PA pa = softmax_pack(s0a, s1a, lsum);

        if (more) { asm volatile("s_waitcnt vmcnt(4)" ::: "memory"); }
        else      { asm volatile("s_waitcnt vmcnt(0)" ::: "memory"); }
        __builtin_amdgcn_s_barrier();
        if (more) stage(t0 + 3);

        f32x16 s0b = {}, s1b = {};
        __builtin_amdgcn_s_setprio(1);
        #pragma unroll
        for (int ds = 0; ds < 4; ++ds) {
            short8 kf0 = *(const short8*)&Ks[bb2][ds*512 + lane*8];
            short8 kf1 = *(const short8*)&Ks[bb2][(4+ds)*512 + lane*8];
            s0b = mfma32(kf0, qf[ds], s0b);
            s1b = mfma32(kf1, qf[ds], s1b);
        }
        #pragma unroll
        for (int ss = 0; ss < 4; ++ss) {
            short8 vf0 = *(const short8*)&Vs[ba][ss*512 + lane*8];
            short8 vf1 = *(const short8*)&Vs[ba][(4+ss)*512 + lane*8];
            ctx0 = mfma32(pa.p[ss], vf0, ctx0);
            ctx1 = mfma32(pa.p[ss], vf1, ctx1);
        }
        __builtin_amdgcn_s_setprio(0);

        PA pb = softmax_pack(s0b, s1b, lsum);

        __builtin_amdgcn_s_setprio(1);
        #pragma unroll
        for (int ss = 0; ss < 4; ++ss) {
            short8 vf0 = *(const short8*)&Vs[bb2][ss*512 + lane*8];
            short8 vf1 = *(const short8*)&Vs[bb2][(4+ss)*512 + lane*8];
            ctx0 = mfma32(pb.p[ss], vf0, ctx0);
            ctx1 = mfma32(pb.p[ss], vf1, ctx1);
        }
        __builtin_amdgcn_s_setprio(0);
    }

    const float linv = 1.0f / lsum;
    #pragma unroll
    for (int r = 0; r < 16; ++r) {
        const int qrow = (r&3) + 8*(r>>2) + 4*h;
        const float nm = __shfl(linv, qrow);
        unsigned short* p = &Ob[(size_t)(q0 + qrow)*DIM + l31];
        p[0]  = bf16rne(ctx0[r] * nm);
        p[32] = bf16rne(ctx1[r] * nm);
    }
}

extern "C" void kernel_launch(void* const* d_in, const int* in_sizes, int n_in,
                              void* d_out, int out_size, void* d_ws, size_t ws_size,
                              hipStream_t stream) {
    const float* x  = (const float*)d_in[0];
    const float* wq = (const float*)d_in[1];
    const float* bq = (const float*)d_in[2];
    const float* wk = (const float*)d_in[3];
    const float* bk = (const float*)d_in[4];
    const float* wv = (const float*)d_in[5];
    const float* bv = (const float*)d_in[6];
    const float* wo = (const float*)d_in[7];
    const float* bo = (const float*)d_in[8];
    float* out = (float*)d_out;

    // ws (ushort): Xb 4M | Wq 1M | Wk 1M | Wv 1M | Wo 1M | Qb 4M | Kpb 4M | Vpb 4M = 40 MB
    // Cb aliases Xb (x dead after gemm_qkv).
    unsigned short* Xb  = (unsigned short*)d_ws;
    unsigned short* Wqb = Xb  + XN;
    unsigned short* Wkb = Wqb + WN;
    unsigned short* Wvb = Wkb + WN;
    unsigned short* Wob = Wvb + WN;
    unsigned short* Qb  = Wob + WN;
    unsigned short* Kpb = Qb  + XN;
    unsigned short* Vpb = Kpb + XN;
    unsigned short* Cb  = Xb;

    prep<<<4096, 256, 0, stream>>>(x, wq, wk, wv, wo, Xb);

    // K/V written directly in fragment-linear layout (pack_kv fused into epilogue)
    gemm_qkv<<<dim3(24, 32), 256, 0, stream>>>(Xb, Wqb, Wkb, Wvb, bq, bk, bv, Qb, Kpb, Vpb);

    attn_mfma2<<<dim3(SEQ/128, BATCH*NHEADS), 256, 0, stream>>>(Qb, Kpb, Vpb, Cb);

    gemm_o<<<dim3(8, 64), 256, 0, stream>>>(Cb, Wob, bo, out);
}

// Round 15
// 128.005 us; speedup vs baseline: 1.1658x; 1.0406x over previous
//
#include <hip/hip_runtime.h>

#define DIM 1024
#define NHEADS 16
#define HDIM 64
#define BATCH 2
#define SEQ 2048
#define MTOT (BATCH*SEQ)
// 1/sqrt(64) * log2(e), folded into Q so softmax uses exp2
#define QSCALE 0.18033688011112042f
#define XN ((size_t)MTOT*DIM)
#define WN ((size_t)DIM*DIM)

typedef __attribute__((ext_vector_type(8))) short short8;
typedef __attribute__((ext_vector_type(4))) float f32x4;
typedef __attribute__((ext_vector_type(16))) float f32x16;
typedef __attribute__((ext_vector_type(2))) int int2v;

static __device__ __forceinline__ unsigned short bf16rne(float f) {
    unsigned u = __builtin_bit_cast(unsigned, f);
    return (unsigned short)((u + 0x7fffu + ((u >> 16) & 1u)) >> 16);
}

// async global->LDS, 16B per lane; LDS dest must be wave-uniform (HW adds lane*16).
static __device__ __forceinline__ void gld16(const void* g, void* l) {
    __builtin_amdgcn_global_load_lds((const __attribute__((address_space(1))) void*)g,
                                     (__attribute__((address_space(3))) void*)l, 16, 0, 0);
}

static __device__ __forceinline__ f32x16 mfma32(short8 a, short8 b, f32x16 c) {
    return __builtin_amdgcn_mfma_f32_32x32x16_bf16(a, b, c, 0, 0, 0);
}

// ---------------- fused f32 -> bf16 convert of x + 4 weights ----------------
__global__ __launch_bounds__(256)
void prep(const float* __restrict__ x, const float* __restrict__ wq, const float* __restrict__ wk,
          const float* __restrict__ wv, const float* __restrict__ wo, unsigned short* __restrict__ dst)
{
    const size_t i = ((size_t)blockIdx.x*256 + threadIdx.x)*8;
    const float* s; size_t o;
    if (i < XN)           { s = x;  o = i; }
    else if (i < XN+WN)   { s = wq; o = i - XN; }
    else if (i < XN+2*WN) { s = wk; o = i - XN - WN; }
    else if (i < XN+3*WN) { s = wv; o = i - XN - 2*WN; }
    else                  { s = wo; o = i - XN - 3*WN; }
    float4 a = *(const float4*)(s + o);
    float4 b = *(const float4*)(s + o + 4);
    uint4 w;
    w.x = (unsigned)bf16rne(a.x) | ((unsigned)bf16rne(a.y) << 16);
    w.y = (unsigned)bf16rne(a.z) | ((unsigned)bf16rne(a.w) << 16);
    w.z = (unsigned)bf16rne(b.x) | ((unsigned)bf16rne(b.y) << 16);
    w.w = (unsigned)bf16rne(b.z) | ((unsigned)bf16rne(b.w) << 16);
    *(uint4*)&dst[i] = w;
}

// ---------------- fused QKV bf16 GEMM, counted-vmcnt pipeline, 3 blocks/CU ----------------
// 128x128 tile, BK=32, 256 thr (4 waves 2x2), wave tile 64x64. r11-proven main loop.
// Q (widx==0): row-major epilogue. K/V (widx==1/2): one-shot LDS-repack epilogue ->
// attention-fragment-linear Kp/Vp with CONTIGUOUS global stores.
__global__ __launch_bounds__(256)
void gemm_qkv(const unsigned short* __restrict__ A,
              const unsigned short* __restrict__ W0, const unsigned short* __restrict__ W1,
              const unsigned short* __restrict__ W2,
              const float* __restrict__ b0, const float* __restrict__ b1, const float* __restrict__ b2,
              unsigned short* __restrict__ o0, unsigned short* __restrict__ o1, unsigned short* __restrict__ o2)
{
    __shared__ __align__(16) unsigned short smem[24576];   // 48 KB: As[3]|Bs[3] ring; epilogue tile
    #define AS(s) (smem + (s)*4096)
    #define BS(s) (smem + 12288 + (s)*4096)
    const int t = threadIdx.x, wid = t >> 6, lane = t & 63;
    const int lr = lane & 15, lg = lane >> 4;
    const int bid = blockIdx.y * 24 + blockIdx.x;
    const int swz = (bid & 7) * 96 + (bid >> 3);
    const int sx = swz % 24, sy = swz / 24;
    const int widx = sx >> 3;
    const int n0 = (sx & 7) << 7;
    const int m0 = sy << 7;
    const unsigned short* W = widx == 0 ? W0 : (widx == 1 ? W1 : W2);
    const float* bias        = widx == 0 ? b0 : (widx == 1 ? b1 : b2);

    const int wm = wid >> 1, wn = wid & 1;
    const int f0 = 2*wid, f1 = f0 + 1;
    const unsigned short* Ag0 = A + (size_t)(m0 + f0*16 + lr)*DIM + lg*8;
    const unsigned short* Ag1 = A + (size_t)(m0 + f1*16 + lr)*DIM + lg*8;
    const unsigned short* Bg0 = W + (size_t)(n0 + f0*16 + lr)*DIM + lg*8;
    const unsigned short* Bg1 = W + (size_t)(n0 + f1*16 + lr)*DIM + lg*8;

    auto stage = [&](int tt, int slot) {
        const int ko = tt * 32;
        gld16(Ag0 + ko, AS(slot) + f0*512); gld16(Ag1 + ko, AS(slot) + f1*512);
        gld16(Bg0 + ko, BS(slot) + f0*512); gld16(Bg1 + ko, BS(slot) + f1*512);
    };

    f32x4 acc[4][4] = {};
    stage(0, 0); stage(1, 1);
    int c0 = 0, c1 = 1, c2 = 2;

    for (int it = 0; it < DIM/32; ++it) {
        if (it < DIM/32 - 2) { asm volatile("s_waitcnt vmcnt(4)" ::: "memory"); }
        else                 { asm volatile("s_waitcnt vmcnt(0)" ::: "memory"); }
        __builtin_amdgcn_s_barrier();
        short8 af[4], bf[4];
        #pragma unroll
        for (int i = 0; i < 4; ++i) af[i] = *(const short8*)(AS(c0) + (wm*4+i)*512 + lane*8);
        #pragma unroll
        for (int i = 0; i < 4; ++i) bf[i] = *(const short8*)(BS(c0) + (wn*4+i)*512 + lane*8);
        if (it + 2 < DIM/32) stage(it + 2, c2);
        __builtin_amdgcn_s_setprio(1);
        #pragma unroll
        for (int mb = 0; mb < 4; ++mb)
            #pragma unroll
            for (int nb = 0; nb < 4; ++nb)
                acc[mb][nb] = __builtin_amdgcn_mfma_f32_16x16x32_bf16(af[mb], bf[nb], acc[mb][nb], 0, 0, 0);
        __builtin_amdgcn_s_setprio(0);
        const int tmp = c0; c0 = c1; c1 = c2; c2 = tmp;
    }

    if (widx == 0) {
        #pragma unroll
        for (int nb = 0; nb < 4; ++nb) {
            const int col = n0 + wn*64 + nb*16 + lr;
            const float bv = bias[col];
            #pragma unroll
            for (int mb = 0; mb < 4; ++mb) {
                #pragma unroll
                for (int j = 0; j < 4; ++j) {
                    const int row = m0 + wm*64 + mb*16 + lg*4 + j;
                    o0[(size_t)row*DIM + col] = bf16rne((acc[mb][nb][j] + bv) * QSCALE);
                }
            }
        }
    } else {
        // K/V: acc -> LDS tile[128][136], then repack fragment-linear, contiguous stores
        unsigned short* outp = (widx == 1) ? o1 : o2;
        const int isV = (widx == 2);
        __syncthreads();
        unsigned short (*tile)[136] = (unsigned short (*)[136])smem;
        #pragma unroll
        for (int nb = 0; nb < 4; ++nb) {
            const int col = wn*64 + nb*16 + lr;
            const float bv = bias[n0 + col];
            #pragma unroll
            for (int mb = 0; mb < 4; ++mb) {
                #pragma unroll
                for (int j = 0; j < 4; ++j)
                    tile[wm*64 + mb*16 + lg*4 + j][col] = bf16rne(acc[mb][nb][j] + bv);
            }
        }
        __syncthreads();
        const int bb  = m0 >> 11;
        const int kt0 = (m0 & (SEQ-1)) >> 6;
        const int hh0 = n0 >> 6;
        #pragma unroll
        for (int shot = 0; shot < 8; ++shot) {
            const int idx = t + shot*256;
            const int tid = idx >> 9;
            const int fr  = (idx >> 6) & 7;
            const int ln  = idx & 63;
            const int ktl = tid & 1, hhl = tid >> 1;
            short8 ov;
            if (isV) {
                const int r0 = ktl*64 + (fr & 3)*16 + (ln >> 5)*8;
                const int c  = hhl*64 + (fr >> 2)*32 + (ln & 31);
                #pragma unroll
                for (int e = 0; e < 8; ++e) ov[e] = (short)tile[r0 + e][c];
            } else {
                const int r  = ktl*64 + (fr >> 2)*32 + (ln & 31);
                const int cc = hhl*64 + (fr & 3)*16 + (ln >> 5)*8;
                ov = *(const short8*)&tile[r][cc];
            }
            unsigned short* dst = outp
                + ((size_t)((bb*NHEADS + hh0 + hhl)*32 + kt0 + ktl))*4096 + fr*512 + ln*8;
            *(short8*)dst = ov;
        }
    }
    #undef AS
    #undef BS
}

// ---------------- O-projection GEMM: 64x128 tile, counted-vmcnt, f32 out ----------------
__global__ __launch_bounds__(256)
void gemm_o(const unsigned short* __restrict__ A, const unsigned short* __restrict__ W,
            const float* __restrict__ bias, float* __restrict__ fo)
{
    __shared__ __align__(16) unsigned short As[3][2048];
    __shared__ __align__(16) unsigned short Bs[3][4096];
    const int t = threadIdx.x, wid = t >> 6, lane = t & 63;
    const int lr = lane & 15, lg = lane >> 4;
    const int bid = blockIdx.y * 8 + blockIdx.x;
    const int swz = (bid & 7) * 64 + (bid >> 3);
    const int n0 = (swz & 7) << 7;
    const int m0 = (swz >> 3) << 6;
    const int wm = wid >> 1, wn = wid & 1;

    const int fa = wid;
    const int g0 = 2*wid, g1 = g0 + 1;
    const unsigned short* Ag  = A + (size_t)(m0 + fa*16 + lr)*DIM + lg*8;
    const unsigned short* Bg0 = W + (size_t)(n0 + g0*16 + lr)*DIM + lg*8;
    const unsigned short* Bg1 = W + (size_t)(n0 + g1*16 + lr)*DIM + lg*8;

    auto stage = [&](int tt, int slot) {
        const int ko = tt * 32;
        gld16(Ag + ko, &As[slot][fa*512]);
        gld16(Bg0 + ko, &Bs[slot][g0*512]); gld16(Bg1 + ko, &Bs[slot][g1*512]);
    };

    f32x4 acc[2][4] = {};
    stage(0, 0); stage(1, 1);
    int c0 = 0, c1 = 1, c2 = 2;

    for (int it = 0; it < DIM/32; ++it) {
        if (it < DIM/32 - 2) { asm volatile("s_waitcnt vmcnt(3)" ::: "memory"); }
        else                 { asm volatile("s_waitcnt vmcnt(0)" ::: "memory"); }
        __builtin_amdgcn_s_barrier();
        short8 af[2], bf[4];
        #pragma unroll
        for (int i = 0; i < 2; ++i) af[i] = *(const short8*)&As[c0][(wm*2+i)*512 + lane*8];
        #pragma unroll
        for (int i = 0; i < 4; ++i) bf[i] = *(const short8*)&Bs[c0][(wn*4+i)*512 + lane*8];
        if (it + 2 < DIM/32) stage(it + 2, c2);
        __builtin_amdgcn_s_setprio(1);
        #pragma unroll
        for (int mb = 0; mb < 2; ++mb)
            #pragma unroll
            for (int nb = 0; nb < 4; ++nb)
                acc[mb][nb] = __builtin_amdgcn_mfma_f32_16x16x32_bf16(af[mb], bf[nb], acc[mb][nb], 0, 0, 0);
        __builtin_amdgcn_s_setprio(0);
        const int tmp = c0; c0 = c1; c1 = c2; c2 = tmp;
    }

    #pragma unroll
    for (int nb = 0; nb < 4; ++nb) {
        const int col = n0 + wn*64 + nb*16 + lr;
        const float bv = bias[col];
        #pragma unroll
        for (int mb = 0; mb < 2; ++mb) {
            #pragma unroll
            for (int j = 0; j < 4; ++j) {
                const int row = m0 + wm*32 + mb*16 + lg*4 + j;
                fo[(size_t)row*DIM + col] = acc[mb][nb][j] + bv;
            }
        }
    }
}

// ---------------- MFMA flash attention: 8-wave blocks, 256 q-rows ----------------
// grid (8, 32) = 256 blocks, 512 thr (8 waves x 32 q-rows). Each staged K/V tile is
// shared by 8 waves (2x the reuse of the 4-wave version): window-instances, barrier
// events, gld16 issues and L2 staging traffic all HALVE at constant math.
// Same 2-tile window + counted vmcnt; wave stages 1 K-frag + 1 V-frag (vmcnt(2)).
struct PA { short8 p[4]; };

static __device__ __forceinline__ PA softmax_pack(const f32x16& s0, const f32x16& s1, float& lsum) {
    float rsum = 0.f;
    unsigned pw0[4][2], pw1[4][2];
    #pragma unroll
    for (int r1 = 0; r1 < 4; ++r1)
        #pragma unroll
        for (int tt = 0; tt < 2; ++tt) {
            float pa_ = __builtin_amdgcn_exp2f(s0[4*r1+2*tt]);
            float pb_ = __builtin_amdgcn_exp2f(s0[4*r1+2*tt+1]);
            float pc_ = __builtin_amdgcn_exp2f(s1[4*r1+2*tt]);
            float pd_ = __builtin_amdgcn_exp2f(s1[4*r1+2*tt+1]);
            rsum += (pa_ + pb_) + (pc_ + pd_);
            asm("v_cvt_pk_bf16_f32 %0, %1, %2" : "=v"(pw0[r1][tt]) : "v"(pa_), "v"(pb_));
            asm("v_cvt_pk_bf16_f32 %0, %1, %2" : "=v"(pw1[r1][tt]) : "v"(pc_), "v"(pd_));
        }
    rsum += __shfl_xor(rsum, 32);
    lsum += rsum;
    PA r;
    #pragma unroll
    for (int ss = 0; ss < 4; ++ss) {
        union { short8 s8; unsigned u[4]; } pu;
        #pragma unroll
        for (int tt = 0; tt < 2; ++tt) {
            const unsigned a = (ss >> 1) ? pw1[2*(ss&1)][tt]   : pw0[2*(ss&1)][tt];
            const unsigned b = (ss >> 1) ? pw1[2*(ss&1)+1][tt] : pw0[2*(ss&1)+1][tt];
            int2v sw = __builtin_amdgcn_permlane32_swap((int)a, (int)b, false, false);
            pu.u[tt]     = (unsigned)sw[0];
            pu.u[2 + tt] = (unsigned)sw[1];
        }
        r.p[ss] = pu.s8;
    }
    return r;
}

__global__ __launch_bounds__(512)
void attn_mfma2(const unsigned short* __restrict__ Q, const unsigned short* __restrict__ Kp,
                const unsigned short* __restrict__ Vp, unsigned short* __restrict__ O)
{
    __shared__ __align__(16) unsigned short Ks[4][4096];
    __shared__ __align__(16) unsigned short Vs[4][4096];
    const int t = threadIdx.x, wid = t >> 6, lane = t & 63;   // wid 0..7
    const int l31 = lane & 31, h = lane >> 5;
    // grid (8, 32) = 256 blocks; swizzle: XCD c gets heads 4c..4c+3
    const int bid = blockIdx.y * 8 + blockIdx.x;
    const int swz = (bid & 7) * 32 + (bid >> 3);
    const int qt = swz & 7, bh = swz >> 3;
    const int b = bh >> 4, hh = bh & 15;
    const size_t qkbase = (size_t)b*SEQ*DIM + (size_t)hh*HDIM;
    const unsigned short* Qb = Q + qkbase;
    unsigned short*       Ob = O + qkbase;
    const int q0 = qt*256 + wid*32;

    short8 qf[4];   // Q as B-operand: lane holds Q[q0+l31][ds*16 + h*8 + e]
    #pragma unroll
    for (int ds = 0; ds < 4; ++ds)
        qf[ds] = *(const short8*)&Qb[(size_t)(q0 + l31)*DIM + ds*16 + h*8];

    // wave stages K frag wid, V frag wid (1 KB contiguous each)
    const unsigned short* Kg0 = Kp + (size_t)bh*32*4096 + wid*512 + lane*8;
    const unsigned short* Vg0 = Vp + (size_t)bh*32*4096 + wid*512 + lane*8;

    auto stage = [&](int tn) {   // tn < 32; 2 gld16 per wave
        const size_t ko = (size_t)tn * 4096;
        const int bb = tn & 3;
        gld16(Kg0 + ko, &Ks[bb][wid*512]);
        gld16(Vg0 + ko, &Vs[bb][wid*512]);
    };

    f32x16 ctx0 = {}, ctx1 = {};
    float lsum = 0.0f;

    stage(0); stage(1);   // 4 loads in flight per wave

    const int NW = SEQ/128;
    for (int w = 0; w < NW; ++w) {
        const int t0 = 2*w;
        const int ba = t0 & 3, bb2 = (t0+1) & 3;
        const bool more = (w + 1 < NW);

        // B1: own stage(t0) landed (stage(t0+1)'s 2 loads stay in flight)
        if (more) { asm volatile("s_waitcnt vmcnt(2)" ::: "memory"); }
        else      { asm volatile("s_waitcnt vmcnt(0)" ::: "memory"); }
        __builtin_amdgcn_s_barrier();
        if (more) stage(t0 + 2);

        f32x16 s0a = {}, s1a = {};
        __builtin_amdgcn_s_setprio(1);
        #pragma unroll
        for (int ds = 0; ds < 4; ++ds) {
            short8 kf0 = *(const short8*)&Ks[ba][ds*512 + lane*8];
            short8 kf1 = *(const short8*)&Ks[ba][(4+ds)*512 + lane*8];
            s0a = mfma32(kf0, qf[ds], s0a);
            s1a = mfma32(kf1, qf[ds], s1a);
        }
        __builtin_amdgcn_s_setprio(0);

        PA pa = softmax_pack(s0a, s1a, lsum);

        // B2: own stage(t0+1) landed; gates stage(t0+3)
        if (more) { asm volatile("s_waitcnt vmcnt(2)" ::: "memory"); }
        else      { asm volatile("s_waitcnt vmcnt(0)" ::: "memory"); }
        __builtin_amdgcn_s_barrier();
        if (more) stage(t0 + 3);

        f32x16 s0b = {}, s1b = {};
        __builtin_amdgcn_s_setprio(1);
        #pragma unroll
        for (int ds = 0; ds < 4; ++ds) {
            short8 kf0 = *(const short8*)&Ks[bb2][ds*512 + lane*8];
            short8 kf1 = *(const short8*)&Ks[bb2][(4+ds)*512 + lane*8];
            s0b = mfma32(kf0, qf[ds], s0b);
            s1b = mfma32(kf1, qf[ds], s1b);
        }
        #pragma unroll
        for (int ss = 0; ss < 4; ++ss) {
            short8 vf0 = *(const short8*)&Vs[ba][ss*512 + lane*8];
            short8 vf1 = *(const short8*)&Vs[ba][(4+ss)*512 + lane*8];
            ctx0 = mfma32(pa.p[ss], vf0, ctx0);
            ctx1 = mfma32(pa.p[ss], vf1, ctx1);
        }
        __builtin_amdgcn_s_setprio(0);

        PA pb = softmax_pack(s0b, s1b, lsum);

        __builtin_amdgcn_s_setprio(1);
        #pragma unroll
        for (int ss = 0; ss < 4; ++ss) {
            short8 vf0 = *(const short8*)&Vs[bb2][ss*512 + lane*8];
            short8 vf1 = *(const short8*)&Vs[bb2][(4+ss)*512 + lane*8];
            ctx0 = mfma32(pb.p[ss], vf0, ctx0);
            ctx1 = mfma32(pb.p[ss], vf1, ctx1);
        }
        __builtin_amdgcn_s_setprio(0);
    }

    const float linv = 1.0f / lsum;
    #pragma unroll
    for (int r = 0; r < 16; ++r) {
        const int qrow = (r&3) + 8*(r>>2) + 4*h;
        const float nm = __shfl(linv, qrow);
        unsigned short* p = &Ob[(size_t)(q0 + qrow)*DIM + l31];
        p[0]  = bf16rne(ctx0[r] * nm);
        p[32] = bf16rne(ctx1[r] * nm);
    }
}

extern "C" void kernel_launch(void* const* d_in, const int* in_sizes, int n_in,
                              void* d_out, int out_size, void* d_ws, size_t ws_size,
                              hipStream_t stream) {
    const float* x  = (const float*)d_in[0];
    const float* wq = (const float*)d_in[1];
    const float* bq = (const float*)d_in[2];
    const float* wk = (const float*)d_in[3];
    const float* bk = (const float*)d_in[4];
    const float* wv = (const float*)d_in[5];
    const float* bv = (const float*)d_in[6];
    const float* wo = (const float*)d_in[7];
    const float* bo = (const float*)d_in[8];
    float* out = (float*)d_out;

    // ws (ushort): Xb 4M | Wq 1M | Wk 1M | Wv 1M | Wo 1M | Qb 4M | Kpb 4M | Vpb 4M = 40 MB
    // Cb aliases Xb (x dead after gemm_qkv).
    unsigned short* Xb  = (unsigned short*)d_ws;
    unsigned short* Wqb = Xb  + XN;
    unsigned short* Wkb = Wqb + WN;
    unsigned short* Wvb = Wkb + WN;
    unsigned short* Wob = Wvb + WN;
    unsigned short* Qb  = Wob + WN;
    unsigned short* Kpb = Qb  + XN;
    unsigned short* Vpb = Kpb + XN;
    unsigned short* Cb  = Xb;

    prep<<<4096, 256, 0, stream>>>(x, wq, wk, wv, wo, Xb);

    // K/V written directly in fragment-linear layout (pack fused into epilogue)
    gemm_qkv<<<dim3(24, 32), 256, 0, stream>>>(Xb, Wqb, Wkb, Wvb, bq, bk, bv, Qb, Kpb, Vpb);

    attn_mfma2<<<dim3(8, BATCH*NHEADS), 512, 0, stream>>>(Qb, Kpb, Vpb, Cb);

    gemm_o<<<dim3(8, 64), 256, 0, stream>>>(Cb, Wob, bo, out);
}